// Round 4
// baseline (301.596 us; speedup 1.0000x reference)
//
#include <hip/hip_runtime.h>
#include <math.h>

#define EPS 1e-5f
#define KEXP 4.8089834696298780f  // log2(e)/0.3 : exp(x/h) == exp2(x*KEXP)

typedef short short8 __attribute__((ext_vector_type(8)));
typedef float f32x4  __attribute__((ext_vector_type(4)));

static __device__ __forceinline__ unsigned short f2bf(float x) {
  unsigned int b = __float_as_uint(x);
  b += 0x7FFFu + ((b >> 16) & 1u);  // RNE
  return (unsigned short)(b >> 16);
}
static __device__ __forceinline__ unsigned encf(float f) {
  unsigned b = __float_as_uint(f);
  return (b & 0x80000000u) ? ~b : (b | 0x80000000u);
}
static __device__ __forceinline__ float decf(unsigned u) {
  return (u & 0x80000000u) ? __uint_as_float(u & 0x7FFFFFFFu)
                           : __uint_as_float(~u);
}

// ---------------------------------------------------------------------------
// prep: normalize column j (over C), cast bf16, write MFMA-fragment-blocked:
//   (j,c) -> uint4 idx ((j>>4)*KC + (c>>5))*64 + ((c>>3)&3)*16 + (j&15)
// ---------------------------------------------------------------------------
template <int C, int HW>
__device__ __forceinline__ void prep_body(const float* __restrict__ f,
                                          uint4* __restrict__ out, int idx) {
  int b = idx / HW, j = idx - b * HW;
  const float* p = f + (size_t)b * C * HW + j;
  float ssq = 0.f;
  for (int c = 0; c < C; ++c) { float v = p[(size_t)c * HW]; ssq = fmaf(v, v, ssq); }
  float inv = 1.0f / (sqrtf(ssq) + EPS);
  constexpr int KC = C >> 5;
  uint4* ob = out + (size_t)b * (HW >> 4) * KC * 64 + (size_t)(j >> 4) * KC * 64 + (j & 15);
  for (int c0 = 0; c0 < C; c0 += 8) {
    unsigned w[4];
#pragma unroll
    for (int h = 0; h < 4; ++h) {
      float v0 = p[(size_t)(c0 + 2 * h) * HW] * inv;
      float v1 = p[(size_t)(c0 + 2 * h + 1) * HW] * inv;
      w[h] = (unsigned)f2bf(v0) | ((unsigned)f2bf(v1) << 16);
    }
    ob[(size_t)(c0 >> 5) * 64 + ((c0 >> 3) & 3) * 16] = make_uint4(w[0], w[1], w[2], w[3]);
  }
}

// prep + init of dE (0xFF), S (0), out (0) in one launch
__global__ __launch_bounds__(256) void prep_all(
    const float* __restrict__ fx1, uint4* __restrict__ fx1B,
    const float* __restrict__ fy1, uint4* __restrict__ fy1B,
    const float* __restrict__ fx2, uint4* __restrict__ fx2B,
    const float* __restrict__ fy2, uint4* __restrict__ fy2B,
    unsigned* __restrict__ dE, float* __restrict__ S, float* __restrict__ out) {
  int bid = blockIdx.x;
  if (bid < 128)       prep_body<128, 4096>(fx1, fx1B, bid * 256 + threadIdx.x);
  else if (bid < 256)  prep_body<128, 4096>(fy1, fy1B, (bid - 128) * 256 + threadIdx.x);
  else if (bid < 288)  prep_body<256, 1024>(fx2, fx2B, (bid - 256) * 256 + threadIdx.x);
  else if (bid < 320)  prep_body<256, 1024>(fy2, fy2B, (bid - 288) * 256 + threadIdx.x);
  else {
    int t = (bid - 320) * 256 + threadIdx.x;  // 16 blocks -> 4096 threads
    for (int k = t; k < 8 * (4096 + 1024); k += 4096) {
      dE[k] = 0xFFFFFFFFu;
      S[k] = 0.f;
    }
    if (t == 0) out[0] = 0.f;
  }
}

// ---------------------------------------------------------------------------
// passA body: partial row-min of d = 1 - sim over a j-slice, atomicMin combine.
// fy fragments double-buffered in registers (prefetch s+1 during MFMAs of s).
// ---------------------------------------------------------------------------
template <int HW, int C, int TI, int JSPLIT>
__device__ __forceinline__ void passA_body(const uint4* __restrict__ fxB,
                                           const uint4* __restrict__ fyB,
                                           unsigned* __restrict__ dminEnc, int blk) {
  constexpr int KC = C / 32;
  constexpr int JB = HW / 16;
  constexpr int IPB = HW / (TI * 16);
  constexpr int JPS = JB / JSPLIT;
  constexpr int TPS = JPS / 4;
  const int lane = threadIdx.x & 63, wv = threadIdx.x >> 6, l15 = lane & 15;
  const int sample = blk / (IPB * JSPLIT);
  const int rem = blk % (IPB * JSPLIT);
  const int ib0 = (rem / JSPLIT) * TI;
  const int jt0 = (rem % JSPLIT) * JPS;
  const size_t sOff = (size_t)sample * JB * KC * 64;
  const uint4* fx = fxB + sOff;
  const uint4* fy = fyB + sOff;

  short8 bf[TI][KC];
#pragma unroll
  for (int ti = 0; ti < TI; ++ti)
#pragma unroll
    for (int kc = 0; kc < KC; ++kc) {
      uint4 t = fx[(size_t)((ib0 + ti) * KC + kc) * 64 + lane];
      bf[ti][kc] = *(short8*)&t;
    }

  float smax[TI];
#pragma unroll
  for (int ti = 0; ti < TI; ++ti) smax[ti] = -1e30f;

  uint4 cur[KC], nxt[KC];
#pragma unroll
  for (int kc = 0; kc < KC; ++kc)
    cur[kc] = fy[(size_t)((jt0 + wv) * KC + kc) * 64 + lane];

  for (int s = 0; s < TPS; ++s) {
    const int sn = (s + 1 < TPS) ? s + 1 : s;
    const int jtn = jt0 + sn * 4 + wv;
#pragma unroll
    for (int kc = 0; kc < KC; ++kc)
      nxt[kc] = fy[(size_t)(jtn * KC + kc) * 64 + lane];

    f32x4 acc[TI];
#pragma unroll
    for (int ti = 0; ti < TI; ++ti)
#pragma unroll
      for (int r = 0; r < 4; ++r) acc[ti][r] = 0.f;
#pragma unroll
    for (int kc = 0; kc < KC; ++kc) {
      short8 a = *(short8*)&cur[kc];
#pragma unroll
      for (int ti = 0; ti < TI; ++ti)
        acc[ti] = __builtin_amdgcn_mfma_f32_16x16x32_bf16(a, bf[ti][kc], acc[ti], 0, 0, 0);
    }
#pragma unroll
    for (int ti = 0; ti < TI; ++ti)
#pragma unroll
      for (int r = 0; r < 4; ++r) smax[ti] = fmaxf(smax[ti], acc[ti][r]);
#pragma unroll
    for (int kc = 0; kc < KC; ++kc) cur[kc] = nxt[kc];
  }

  __shared__ float red[4][TI][16];
#pragma unroll
  for (int ti = 0; ti < TI; ++ti) {
    float v = smax[ti];
    v = fmaxf(v, __shfl_xor(v, 16));
    v = fmaxf(v, __shfl_xor(v, 32));
    if (lane < 16) red[wv][ti][l15] = v;
  }
  __syncthreads();
  if (threadIdx.x < TI * 16) {
    const int ti = threadIdx.x >> 4, il = threadIdx.x & 15;
    float v = fmaxf(fmaxf(red[0][ti][il], red[1][ti][il]),
                    fmaxf(red[2][ti][il], red[3][ti][il]));
    atomicMin(&dminEnc[(size_t)sample * HW + (ib0 + ti) * 16 + il], encf(1.0f - v));
  }
}

// ---------------------------------------------------------------------------
// passB body: recompute dots, partial sum_j exp2(c0 + sim*c1), atomicAdd.
// ---------------------------------------------------------------------------
template <int HW, int C, int TI, int JSPLIT>
__device__ __forceinline__ void passB_body(const uint4* __restrict__ fxB,
                                           const uint4* __restrict__ fyB,
                                           const unsigned* __restrict__ dminEnc,
                                           float* __restrict__ Ssum, int blk) {
  constexpr int KC = C / 32;
  constexpr int JB = HW / 16;
  constexpr int IPB = HW / (TI * 16);
  constexpr int JPS = JB / JSPLIT;
  constexpr int TPS = JPS / 4;
  const int lane = threadIdx.x & 63, wv = threadIdx.x >> 6, l15 = lane & 15;
  const int sample = blk / (IPB * JSPLIT);
  const int rem = blk % (IPB * JSPLIT);
  const int ib0 = (rem / JSPLIT) * TI;
  const int jt0 = (rem % JSPLIT) * JPS;
  const size_t sOff = (size_t)sample * JB * KC * 64;
  const uint4* fx = fxB + sOff;
  const uint4* fy = fyB + sOff;

  short8 bf[TI][KC];
#pragma unroll
  for (int ti = 0; ti < TI; ++ti)
#pragma unroll
    for (int kc = 0; kc < KC; ++kc) {
      uint4 t = fx[(size_t)((ib0 + ti) * KC + kc) * 64 + lane];
      bf[ti][kc] = *(short8*)&t;
    }

  float c0v[TI], c1v[TI];
#pragma unroll
  for (int ti = 0; ti < TI; ++ti) {
    float dmin = decf(dminEnc[(size_t)sample * HW + (ib0 + ti) * 16 + l15]);
    float dinv = 1.0f / (dmin + EPS);
    c1v[ti] = dinv * KEXP;
    c0v[ti] = (1.0f - dinv) * KEXP;
  }

  float ssum[TI];
#pragma unroll
  for (int ti = 0; ti < TI; ++ti) ssum[ti] = 0.f;

  uint4 cur[KC], nxt[KC];
#pragma unroll
  for (int kc = 0; kc < KC; ++kc)
    cur[kc] = fy[(size_t)((jt0 + wv) * KC + kc) * 64 + lane];

  for (int s = 0; s < TPS; ++s) {
    const int sn = (s + 1 < TPS) ? s + 1 : s;
    const int jtn = jt0 + sn * 4 + wv;
#pragma unroll
    for (int kc = 0; kc < KC; ++kc)
      nxt[kc] = fy[(size_t)(jtn * KC + kc) * 64 + lane];

    f32x4 acc[TI];
#pragma unroll
    for (int ti = 0; ti < TI; ++ti)
#pragma unroll
      for (int r = 0; r < 4; ++r) acc[ti][r] = 0.f;
#pragma unroll
    for (int kc = 0; kc < KC; ++kc) {
      short8 a = *(short8*)&cur[kc];
#pragma unroll
      for (int ti = 0; ti < TI; ++ti)
        acc[ti] = __builtin_amdgcn_mfma_f32_16x16x32_bf16(a, bf[ti][kc], acc[ti], 0, 0, 0);
    }
#pragma unroll
    for (int ti = 0; ti < TI; ++ti)
#pragma unroll
      for (int r = 0; r < 4; ++r)
        ssum[ti] += __builtin_amdgcn_exp2f(fmaf(acc[ti][r], c1v[ti], c0v[ti]));
#pragma unroll
    for (int kc = 0; kc < KC; ++kc) cur[kc] = nxt[kc];
  }

  __shared__ float red[4][TI][16];
#pragma unroll
  for (int ti = 0; ti < TI; ++ti) {
    float v = ssum[ti];
    v += __shfl_xor(v, 16);
    v += __shfl_xor(v, 32);
    if (lane < 16) red[wv][ti][l15] = v;
  }
  __syncthreads();
  if (threadIdx.x < TI * 16) {
    const int ti = threadIdx.x >> 4, il = threadIdx.x & 15;
    float v = red[0][ti][il] + red[1][ti][il] + red[2][ti][il] + red[3][ti][il];
    atomicAdd(&Ssum[(size_t)sample * HW + (ib0 + ti) * 16 + il], v);
  }
}

// fused dispatchers: layer1 = 2048 blocks (TI=4, JSPLIT=4), layer2 = 1024
// blocks (TI=2, JSPLIT=4).  min-waves 3 -> 170 unified regs/wave.
__global__ __launch_bounds__(256, 3) void passA_all(
    const uint4* __restrict__ fx1B, const uint4* __restrict__ fy1B,
    unsigned* __restrict__ dE1,
    const uint4* __restrict__ fx2B, const uint4* __restrict__ fy2B,
    unsigned* __restrict__ dE2) {
  if (blockIdx.x < 2048) passA_body<4096, 128, 4, 4>(fx1B, fy1B, dE1, blockIdx.x);
  else                   passA_body<1024, 256, 2, 4>(fx2B, fy2B, dE2, blockIdx.x - 2048);
}

__global__ __launch_bounds__(256, 3) void passB_all(
    const uint4* __restrict__ fx1B, const uint4* __restrict__ fy1B,
    const unsigned* __restrict__ dE1, float* __restrict__ S1,
    const uint4* __restrict__ fx2B, const uint4* __restrict__ fy2B,
    const unsigned* __restrict__ dE2, float* __restrict__ S2) {
  if (blockIdx.x < 2048) passB_body<4096, 128, 4, 4>(fx1B, fy1B, dE1, S1, blockIdx.x);
  else                   passB_body<1024, 256, 2, 4>(fx2B, fy2B, dE2, S2, blockIdx.x - 2048);
}

// ---------------------------------------------------------------------------
// reduce_out: one block per sample; atomicAdd(-log(cx+EPS)/16) into out[0].
// ---------------------------------------------------------------------------
__global__ __launch_bounds__(256) void reduce_out(
    const unsigned* __restrict__ dE1, const float* __restrict__ S1,
    const unsigned* __restrict__ dE2, const float* __restrict__ S2,
    float* __restrict__ out) {
  const int s = blockIdx.x;
  const unsigned* dE;
  const float* Sp;
  int HW;
  if (s < 8) { dE = dE1 + (size_t)s * 4096; Sp = S1 + (size_t)s * 4096; HW = 4096; }
  else       { dE = dE2 + (size_t)(s - 8) * 1024; Sp = S2 + (size_t)(s - 8) * 1024; HW = 1024; }
  float t = 0.f;
  for (int i = threadIdx.x; i < HW; i += 256) {
    float dmin = decf(dE[i]);
    float dinv = 1.0f / (dmin + EPS);
    float wmx = __builtin_amdgcn_exp2f((1.0f - dmin * dinv) * KEXP);
    t += wmx / (Sp[i] + EPS);
  }
  __shared__ float red[4];
  t += __shfl_xor(t, 1);  t += __shfl_xor(t, 2);  t += __shfl_xor(t, 4);
  t += __shfl_xor(t, 8);  t += __shfl_xor(t, 16); t += __shfl_xor(t, 32);
  if ((threadIdx.x & 63) == 0) red[threadIdx.x >> 6] = t;
  __syncthreads();
  if (threadIdx.x == 0) {
    float cx = (red[0] + red[1] + red[2] + red[3]) / (float)HW;
    atomicAdd(out, -logf(cx + EPS) * (1.0f / 16.0f));
  }
}

extern "C" void kernel_launch(void* const* d_in, const int* in_sizes, int n_in,
                              void* d_out, int out_size, void* d_ws, size_t ws_size,
                              hipStream_t stream) {
  const float* fx1 = (const float*)d_in[0];  // (8,128,64,64)
  const float* fy1 = (const float*)d_in[1];
  const float* fx2 = (const float*)d_in[2];  // (8,256,32,32)
  const float* fy2 = (const float*)d_in[3];
  float* out = (float*)d_out;

  const int B = 8, HW1 = 4096, HW2 = 1024;

  char* w = (char*)d_ws;
  unsigned* dE1 = (unsigned*)w;                      // 8*4096 u32
  unsigned* dE2 = dE1 + (size_t)B * HW1;             // 8*1024 u32
  float*    S1  = (float*)(dE2 + (size_t)B * HW2);   // 8*4096 f
  float*    S2  = S1 + (size_t)B * HW1;              // 8*1024 f
  uint4*    fx1B = (uint4*)((char*)(S2 + (size_t)B * HW2) + 1024);
  const size_t n1 = (size_t)B * (HW1 / 16) * (128 / 32) * 64;  // 8 MB
  const size_t n2 = (size_t)B * (HW2 / 16) * (256 / 32) * 64;  // 4 MB
  uint4* fy1B = fx1B + n1;
  uint4* fx2B = fy1B + n1;
  uint4* fy2B = fx2B + n2;   // total ~24.4 MB

  prep_all<<<336, 256, 0, stream>>>(fx1, fx1B, fy1, fy1B, fx2, fx2B, fy2, fy2B,
                                    dE1, S1, out);
  passA_all<<<3072, 256, 0, stream>>>(fx1B, fy1B, dE1, fx2B, fy2B, dE2);
  passB_all<<<3072, 256, 0, stream>>>(fx1B, fy1B, dE1, S1, fx2B, fy2B, dE2, S2);
  reduce_out<<<16, 256, 0, stream>>>(dE1, S1, dE2, S2, out);
}

// Round 5
// 196.421 us; speedup vs baseline: 1.5355x; 1.5355x over previous
//
#include <hip/hip_runtime.h>
#include <math.h>

#define EPS 1e-5f
#define KEXP 4.8089834696298780f  // log2(e)/0.3 : exp(x/h) == exp2(x*KEXP)

typedef short short8 __attribute__((ext_vector_type(8)));
typedef float f32x4  __attribute__((ext_vector_type(4)));

static __device__ __forceinline__ unsigned short f2bf(float x) {
  unsigned int b = __float_as_uint(x);
  b += 0x7FFFu + ((b >> 16) & 1u);  // RNE
  return (unsigned short)(b >> 16);
}
static __device__ __forceinline__ unsigned encf(float f) {
  unsigned b = __float_as_uint(f);
  return (b & 0x80000000u) ? ~b : (b | 0x80000000u);
}
static __device__ __forceinline__ float decf(unsigned u) {
  return (u & 0x80000000u) ? __uint_as_float(u & 0x7FFFFFFFu)
                           : __uint_as_float(~u);
}

// ---------------------------------------------------------------------------
// prep: normalize column j (over C), cast bf16, write MFMA-fragment-blocked:
//   (j,c) -> uint4 idx ((j>>4)*KC + (c>>5))*64 + ((c>>3)&3)*16 + (j&15)
// ---------------------------------------------------------------------------
template <int C, int HW>
__device__ __forceinline__ void prep_body(const float* __restrict__ f,
                                          uint4* __restrict__ out, int idx) {
  int b = idx / HW, j = idx - b * HW;
  const float* p = f + (size_t)b * C * HW + j;
  float ssq = 0.f;
  for (int c = 0; c < C; ++c) { float v = p[(size_t)c * HW]; ssq = fmaf(v, v, ssq); }
  float inv = 1.0f / (sqrtf(ssq) + EPS);
  constexpr int KC = C >> 5;
  uint4* ob = out + (size_t)b * (HW >> 4) * KC * 64 + (size_t)(j >> 4) * KC * 64 + (j & 15);
  for (int c0 = 0; c0 < C; c0 += 8) {
    unsigned w[4];
#pragma unroll
    for (int h = 0; h < 4; ++h) {
      float v0 = p[(size_t)(c0 + 2 * h) * HW] * inv;
      float v1 = p[(size_t)(c0 + 2 * h + 1) * HW] * inv;
      w[h] = (unsigned)f2bf(v0) | ((unsigned)f2bf(v1) << 16);
    }
    ob[(size_t)(c0 >> 5) * 64 + ((c0 >> 3) & 3) * 16] = make_uint4(w[0], w[1], w[2], w[3]);
  }
}

// prep + init of dE (0xFF), S (0), out (0) in one launch
__global__ __launch_bounds__(256) void prep_all(
    const float* __restrict__ fx1, uint4* __restrict__ fx1B,
    const float* __restrict__ fy1, uint4* __restrict__ fy1B,
    const float* __restrict__ fx2, uint4* __restrict__ fx2B,
    const float* __restrict__ fy2, uint4* __restrict__ fy2B,
    unsigned* __restrict__ dE, float* __restrict__ S, float* __restrict__ out) {
  int bid = blockIdx.x;
  if (bid < 128)       prep_body<128, 4096>(fx1, fx1B, bid * 256 + threadIdx.x);
  else if (bid < 256)  prep_body<128, 4096>(fy1, fy1B, (bid - 128) * 256 + threadIdx.x);
  else if (bid < 288)  prep_body<256, 1024>(fx2, fx2B, (bid - 256) * 256 + threadIdx.x);
  else if (bid < 320)  prep_body<256, 1024>(fy2, fy2B, (bid - 288) * 256 + threadIdx.x);
  else {
    int t = (bid - 320) * 256 + threadIdx.x;  // 16 blocks -> 4096 threads
    for (int k = t; k < 8 * (4096 + 1024); k += 4096) {
      dE[k] = 0xFFFFFFFFu;
      S[k] = 0.f;
    }
    if (t == 0) out[0] = 0.f;
  }
}

// ---------------------------------------------------------------------------
// passA: per (sample, i-block of TI*16, j-slice) partial row-min of d=1-sim,
// combined via encoded atomicMin. XCD-affinity: sample = blockIdx % 8 so each
// XCD's L2 holds exactly one sample's fx+fy blocked arrays (~2 MB).
// A (rows of D) = fy j-tile streamed from L2; B (cols) = fx, in registers.
// No register double-buffer (round 4 showed it spills; round 3 fit fine).
// ---------------------------------------------------------------------------
template <int HW, int C, int TI, int JSPLIT>
__global__ __launch_bounds__(256, 4) void passA(
    const uint4* __restrict__ fxB, const uint4* __restrict__ fyB,
    unsigned* __restrict__ dminEnc) {
  constexpr int KC = C / 32;
  constexpr int JB = HW / 16;
  constexpr int JPS = JB / JSPLIT;
  constexpr int TPS = JPS / 4;
  const int lane = threadIdx.x & 63, wv = threadIdx.x >> 6, l15 = lane & 15;
  const int sample = blockIdx.x & 7;       // XCD affinity
  const int rem = blockIdx.x >> 3;         // [0, IPB*JSPLIT)
  const int ib0 = (rem / JSPLIT) * TI;
  const int jt0 = (rem % JSPLIT) * JPS;
  const size_t sOff = (size_t)sample * JB * KC * 64;
  const uint4* fx = fxB + sOff;
  const uint4* fy = fyB + sOff;

  short8 bf[TI][KC];
#pragma unroll
  for (int ti = 0; ti < TI; ++ti)
#pragma unroll
    for (int kc = 0; kc < KC; ++kc) {
      uint4 t = fx[(size_t)((ib0 + ti) * KC + kc) * 64 + lane];
      bf[ti][kc] = *(short8*)&t;
    }

  float smax[TI];
#pragma unroll
  for (int ti = 0; ti < TI; ++ti) smax[ti] = -1e30f;

  for (int s = 0; s < TPS; ++s) {
    const int jt = jt0 + s * 4 + wv;
    uint4 af[KC];
#pragma unroll
    for (int kc = 0; kc < KC; ++kc) af[kc] = fy[(size_t)(jt * KC + kc) * 64 + lane];
    f32x4 acc[TI];
#pragma unroll
    for (int ti = 0; ti < TI; ++ti)
#pragma unroll
      for (int r = 0; r < 4; ++r) acc[ti][r] = 0.f;
#pragma unroll
    for (int kc = 0; kc < KC; ++kc) {
      short8 a = *(short8*)&af[kc];
#pragma unroll
      for (int ti = 0; ti < TI; ++ti)
        acc[ti] = __builtin_amdgcn_mfma_f32_16x16x32_bf16(a, bf[ti][kc], acc[ti], 0, 0, 0);
    }
#pragma unroll
    for (int ti = 0; ti < TI; ++ti)
#pragma unroll
      for (int r = 0; r < 4; ++r) smax[ti] = fmaxf(smax[ti], acc[ti][r]);
  }

  __shared__ float red[4][TI][16];
#pragma unroll
  for (int ti = 0; ti < TI; ++ti) {
    float v = smax[ti];
    v = fmaxf(v, __shfl_xor(v, 16));
    v = fmaxf(v, __shfl_xor(v, 32));
    if (lane < 16) red[wv][ti][l15] = v;
  }
  __syncthreads();
  if (threadIdx.x < TI * 16) {
    const int ti = threadIdx.x >> 4, il = threadIdx.x & 15;
    float v = fmaxf(fmaxf(red[0][ti][il], red[1][ti][il]),
                    fmaxf(red[2][ti][il], red[3][ti][il]));
    atomicMin(&dminEnc[(size_t)sample * HW + (ib0 + ti) * 16 + il], encf(1.0f - v));
  }
}

// ---------------------------------------------------------------------------
// passB: recompute dots, partial sum_j exp2(c0 + sim*c1), atomicAdd combine.
// ---------------------------------------------------------------------------
template <int HW, int C, int TI, int JSPLIT>
__global__ __launch_bounds__(256, 4) void passB(
    const uint4* __restrict__ fxB, const uint4* __restrict__ fyB,
    const unsigned* __restrict__ dminEnc, float* __restrict__ Ssum) {
  constexpr int KC = C / 32;
  constexpr int JB = HW / 16;
  constexpr int JPS = JB / JSPLIT;
  constexpr int TPS = JPS / 4;
  const int lane = threadIdx.x & 63, wv = threadIdx.x >> 6, l15 = lane & 15;
  const int sample = blockIdx.x & 7;       // XCD affinity
  const int rem = blockIdx.x >> 3;
  const int ib0 = (rem / JSPLIT) * TI;
  const int jt0 = (rem % JSPLIT) * JPS;
  const size_t sOff = (size_t)sample * JB * KC * 64;
  const uint4* fx = fxB + sOff;
  const uint4* fy = fyB + sOff;

  short8 bf[TI][KC];
#pragma unroll
  for (int ti = 0; ti < TI; ++ti)
#pragma unroll
    for (int kc = 0; kc < KC; ++kc) {
      uint4 t = fx[(size_t)((ib0 + ti) * KC + kc) * 64 + lane];
      bf[ti][kc] = *(short8*)&t;
    }

  float c0v[TI], c1v[TI];
#pragma unroll
  for (int ti = 0; ti < TI; ++ti) {
    float dmin = decf(dminEnc[(size_t)sample * HW + (ib0 + ti) * 16 + l15]);
    float dinv = 1.0f / (dmin + EPS);
    c1v[ti] = dinv * KEXP;
    c0v[ti] = (1.0f - dinv) * KEXP;
  }

  float ssum[TI];
#pragma unroll
  for (int ti = 0; ti < TI; ++ti) ssum[ti] = 0.f;

  for (int s = 0; s < TPS; ++s) {
    const int jt = jt0 + s * 4 + wv;
    uint4 af[KC];
#pragma unroll
    for (int kc = 0; kc < KC; ++kc) af[kc] = fy[(size_t)(jt * KC + kc) * 64 + lane];
    f32x4 acc[TI];
#pragma unroll
    for (int ti = 0; ti < TI; ++ti)
#pragma unroll
      for (int r = 0; r < 4; ++r) acc[ti][r] = 0.f;
#pragma unroll
    for (int kc = 0; kc < KC; ++kc) {
      short8 a = *(short8*)&af[kc];
#pragma unroll
      for (int ti = 0; ti < TI; ++ti)
        acc[ti] = __builtin_amdgcn_mfma_f32_16x16x32_bf16(a, bf[ti][kc], acc[ti], 0, 0, 0);
    }
#pragma unroll
    for (int ti = 0; ti < TI; ++ti)
#pragma unroll
      for (int r = 0; r < 4; ++r)
        ssum[ti] += __builtin_amdgcn_exp2f(fmaf(acc[ti][r], c1v[ti], c0v[ti]));
  }

  __shared__ float red[4][TI][16];
#pragma unroll
  for (int ti = 0; ti < TI; ++ti) {
    float v = ssum[ti];
    v += __shfl_xor(v, 16);
    v += __shfl_xor(v, 32);
    if (lane < 16) red[wv][ti][l15] = v;
  }
  __syncthreads();
  if (threadIdx.x < TI * 16) {
    const int ti = threadIdx.x >> 4, il = threadIdx.x & 15;
    float v = red[0][ti][il] + red[1][ti][il] + red[2][ti][il] + red[3][ti][il];
    atomicAdd(&Ssum[(size_t)sample * HW + (ib0 + ti) * 16 + il], v);
  }
}

// ---------------------------------------------------------------------------
// reduce_out: one block per sample; atomicAdd(-log(cx+EPS)/16) into out[0].
// ---------------------------------------------------------------------------
__global__ __launch_bounds__(256) void reduce_out(
    const unsigned* __restrict__ dE1, const float* __restrict__ S1,
    const unsigned* __restrict__ dE2, const float* __restrict__ S2,
    float* __restrict__ out) {
  const int s = blockIdx.x;
  const unsigned* dE;
  const float* Sp;
  int HW;
  if (s < 8) { dE = dE1 + (size_t)s * 4096; Sp = S1 + (size_t)s * 4096; HW = 4096; }
  else       { dE = dE2 + (size_t)(s - 8) * 1024; Sp = S2 + (size_t)(s - 8) * 1024; HW = 1024; }
  float t = 0.f;
  for (int i = threadIdx.x; i < HW; i += 256) {
    float dmin = decf(dE[i]);
    float dinv = 1.0f / (dmin + EPS);
    float wmx = __builtin_amdgcn_exp2f((1.0f - dmin * dinv) * KEXP);
    t += wmx / (Sp[i] + EPS);
  }
  __shared__ float red[4];
  t += __shfl_xor(t, 1);  t += __shfl_xor(t, 2);  t += __shfl_xor(t, 4);
  t += __shfl_xor(t, 8);  t += __shfl_xor(t, 16); t += __shfl_xor(t, 32);
  if ((threadIdx.x & 63) == 0) red[threadIdx.x >> 6] = t;
  __syncthreads();
  if (threadIdx.x == 0) {
    float cx = (red[0] + red[1] + red[2] + red[3]) / (float)HW;
    atomicAdd(out, -logf(cx + EPS) * (1.0f / 16.0f));
  }
}

extern "C" void kernel_launch(void* const* d_in, const int* in_sizes, int n_in,
                              void* d_out, int out_size, void* d_ws, size_t ws_size,
                              hipStream_t stream) {
  const float* fx1 = (const float*)d_in[0];  // (8,128,64,64)
  const float* fy1 = (const float*)d_in[1];
  const float* fx2 = (const float*)d_in[2];  // (8,256,32,32)
  const float* fy2 = (const float*)d_in[3];
  float* out = (float*)d_out;

  const int B = 8, HW1 = 4096, HW2 = 1024;

  char* w = (char*)d_ws;
  unsigned* dE1 = (unsigned*)w;                      // 8*4096 u32
  unsigned* dE2 = dE1 + (size_t)B * HW1;             // 8*1024 u32
  float*    S1  = (float*)(dE2 + (size_t)B * HW2);   // 8*4096 f
  float*    S2  = S1 + (size_t)B * HW1;              // 8*1024 f
  uint4*    fx1B = (uint4*)((char*)(S2 + (size_t)B * HW2) + 1024);
  const size_t n1 = (size_t)B * (HW1 / 16) * (128 / 32) * 64;  // 8 MB
  const size_t n2 = (size_t)B * (HW2 / 16) * (256 / 32) * 64;  // 4 MB
  uint4* fy1B = fx1B + n1;
  uint4* fx2B = fy1B + n1;
  uint4* fy2B = fx2B + n2;   // total ~24.4 MB

  prep_all<<<336, 256, 0, stream>>>(fx1, fx1B, fy1, fy1B, fx2, fx2B, fy2, fy2B,
                                    dE1, S1, out);

  // layer1: TI=4 (i-width 64), JSPLIT=2 -> 8*64*2 = 1024 blocks (128/sample)
  // layer2: TI=2 (i-width 32), JSPLIT=4 -> 8*32*4 = 1024 blocks (128/sample)
  passA<4096, 128, 4, 2><<<1024, 256, 0, stream>>>(fx1B, fy1B, dE1);
  passA<1024, 256, 2, 4><<<1024, 256, 0, stream>>>(fx2B, fy2B, dE2);
  passB<4096, 128, 4, 2><<<1024, 256, 0, stream>>>(fx1B, fy1B, dE1, S1);
  passB<1024, 256, 2, 4><<<1024, 256, 0, stream>>>(fx2B, fy2B, dE2, S2);

  reduce_out<<<16, 256, 0, stream>>>(dE1, S1, dE2, S2, out);
}

// Round 6
// 188.617 us; speedup vs baseline: 1.5990x; 1.0414x over previous
//
#include <hip/hip_runtime.h>
#include <math.h>

#define EPS 1e-5f
#define KEXP 4.8089834696298780f  // log2(e)/0.3 : exp(x/h) == exp2(x*KEXP)

typedef short short8 __attribute__((ext_vector_type(8)));
typedef float f32x4  __attribute__((ext_vector_type(4)));

static __device__ __forceinline__ unsigned short f2bf(float x) {
  unsigned int b = __float_as_uint(x);
  b += 0x7FFFu + ((b >> 16) & 1u);  // RNE
  return (unsigned short)(b >> 16);
}
static __device__ __forceinline__ unsigned encf(float f) {
  unsigned b = __float_as_uint(f);
  return (b & 0x80000000u) ? ~b : (b | 0x80000000u);
}
static __device__ __forceinline__ float decf(unsigned u) {
  return (u & 0x80000000u) ? __uint_as_float(u & 0x7FFFFFFFu)
                           : __uint_as_float(~u);
}

// async global->LDS, 16B per lane (lane l lands at lds_base + 16*l)
static __device__ __forceinline__ void dma16(const uint4* g, uint4* l) {
  __builtin_amdgcn_global_load_lds(
      (const __attribute__((address_space(1))) unsigned int*)g,
      (__attribute__((address_space(3))) unsigned int*)l, 16, 0, 0);
}

// ---------------------------------------------------------------------------
// prep: normalize column j (over C), cast bf16, write MFMA-fragment-blocked:
//   (j,c) -> uint4 idx ((j>>4)*KC + (c>>5))*64 + ((c>>3)&3)*16 + (j&15)
// A 16x16x32 fragment for (j-tile, k-chunk) is chunk_base + lane*16B.
// ---------------------------------------------------------------------------
template <int C, int HW>
__device__ __forceinline__ void prep_body(const float* __restrict__ f,
                                          uint4* __restrict__ out, int idx) {
  int b = idx / HW, j = idx - b * HW;
  const float* p = f + (size_t)b * C * HW + j;
  float ssq = 0.f;
  for (int c = 0; c < C; ++c) { float v = p[(size_t)c * HW]; ssq = fmaf(v, v, ssq); }
  float inv = 1.0f / (sqrtf(ssq) + EPS);
  constexpr int KC = C >> 5;
  uint4* ob = out + (size_t)b * (HW >> 4) * KC * 64 + (size_t)(j >> 4) * KC * 64 + (j & 15);
  for (int c0 = 0; c0 < C; c0 += 8) {
    unsigned w[4];
#pragma unroll
    for (int h = 0; h < 4; ++h) {
      float v0 = p[(size_t)(c0 + 2 * h) * HW] * inv;
      float v1 = p[(size_t)(c0 + 2 * h + 1) * HW] * inv;
      w[h] = (unsigned)f2bf(v0) | ((unsigned)f2bf(v1) << 16);
    }
    ob[(size_t)(c0 >> 5) * 64 + ((c0 >> 3) & 3) * 16] = make_uint4(w[0], w[1], w[2], w[3]);
  }
}

// prep + init of dE (0xFF), S (0), out (0) in one launch
__global__ __launch_bounds__(256) void prep_all(
    const float* __restrict__ fx1, uint4* __restrict__ fx1B,
    const float* __restrict__ fy1, uint4* __restrict__ fy1B,
    const float* __restrict__ fx2, uint4* __restrict__ fx2B,
    const float* __restrict__ fy2, uint4* __restrict__ fy2B,
    unsigned* __restrict__ dE, float* __restrict__ S, float* __restrict__ out) {
  int bid = blockIdx.x;
  if (bid < 128)       prep_body<128, 4096>(fx1, fx1B, bid * 256 + threadIdx.x);
  else if (bid < 256)  prep_body<128, 4096>(fy1, fy1B, (bid - 128) * 256 + threadIdx.x);
  else if (bid < 288)  prep_body<256, 1024>(fx2, fx2B, (bid - 256) * 256 + threadIdx.x);
  else if (bid < 320)  prep_body<256, 1024>(fy2, fy2B, (bid - 288) * 256 + threadIdx.x);
  else {
    int t = (bid - 320) * 256 + threadIdx.x;  // 16 blocks -> 4096 threads
    for (int k = t; k < 8 * (4096 + 1024); k += 4096) {
      dE[k] = 0xFFFFFFFFu;
      S[k] = 0.f;
    }
    if (t == 0) out[0] = 0.f;
  }
}

// ---------------------------------------------------------------------------
// passA: block = 4 waves with DISTINCT i-ranges (wave wv owns TI 16-wide
// i-tiles), sharing each fy j-tile via LDS (global_load_lds, double-buffered).
// Partial row-min of d=1-sim over the block's j-slice; encoded atomicMin.
// XCD affinity: sample = blockIdx & 7 (per-XCD L2 holds one sample, ~2 MB).
// ---------------------------------------------------------------------------
template <int HW, int C, int TI, int JSPLIT>
__global__ __launch_bounds__(256, 4) void passA(
    const uint4* __restrict__ fxB, const uint4* __restrict__ fyB,
    unsigned* __restrict__ dminEnc) {
  constexpr int KC = C / 32;         // 32-k chunks (1 KB each in a tile)
  constexpr int JB = HW / 16;        // j-tiles per sample
  constexpr int IBW = 4 * TI;        // i-tiles per block
  constexpr int JPS = JB / JSPLIT;   // j-tiles (= steps) per block
  const int lane = threadIdx.x & 63, wv = threadIdx.x >> 6, l15 = lane & 15;
  const int sample = blockIdx.x & 7;
  const int rem = blockIdx.x >> 3;
  const int ib = (rem / JSPLIT) * IBW + wv * TI;   // this wave's first i-tile
  const int jt0 = (rem % JSPLIT) * JPS;
  const size_t sOff = (size_t)sample * JB * KC * 64;
  const uint4* fx = fxB + sOff;
  const uint4* fy = fyB + sOff;

  __shared__ uint4 sbuf[2][KC * 64];

  // stage j-tile jt into sbuf[buf]: tile is KC*64 contiguous uint4s
  auto stage = [&](int jt, int buf) {
    const uint4* g = fy + (size_t)jt * KC * 64;
#pragma unroll
    for (int r = 0; r < KC / 4; ++r) {
      const int t = threadIdx.x + r * 256;
      dma16(g + t, &sbuf[buf][t]);
    }
  };

  stage(jt0, 0);  // prologue DMA

  // persistent fx fragments (B operand, i = cols of D)
  short8 bf[TI][KC];
#pragma unroll
  for (int ti = 0; ti < TI; ++ti)
#pragma unroll
    for (int kc = 0; kc < KC; ++kc) {
      uint4 t = fx[(size_t)((ib + ti) * KC + kc) * 64 + lane];
      bf[ti][kc] = *(short8*)&t;
    }

  float smax[TI];
#pragma unroll
  for (int ti = 0; ti < TI; ++ti) smax[ti] = -1e30f;

  for (int s = 0; s < JPS; ++s) {
    const int cur = s & 1;
    __syncthreads();                       // tile s ready; prev reads done
    if (s + 1 < JPS) stage(jt0 + s + 1, cur ^ 1);

    f32x4 acc[TI];
#pragma unroll
    for (int ti = 0; ti < TI; ++ti)
#pragma unroll
      for (int r = 0; r < 4; ++r) acc[ti][r] = 0.f;
#pragma unroll
    for (int kc = 0; kc < KC; ++kc) {
      uint4 t = sbuf[cur][kc * 64 + lane];
      short8 a = *(short8*)&t;
#pragma unroll
      for (int ti = 0; ti < TI; ++ti)
        acc[ti] = __builtin_amdgcn_mfma_f32_16x16x32_bf16(a, bf[ti][kc], acc[ti], 0, 0, 0);
    }
#pragma unroll
    for (int ti = 0; ti < TI; ++ti)
#pragma unroll
      for (int r = 0; r < 4; ++r) smax[ti] = fmaxf(smax[ti], acc[ti][r]);
  }

  // in-wave reduction only (waves own private i-tiles)
#pragma unroll
  for (int ti = 0; ti < TI; ++ti) {
    float v = smax[ti];
    v = fmaxf(v, __shfl_xor(v, 16));
    v = fmaxf(v, __shfl_xor(v, 32));
    if (lane < 16)
      atomicMin(&dminEnc[(size_t)sample * HW + (ib + ti) * 16 + l15],
                encf(1.0f - v));
  }
}

// ---------------------------------------------------------------------------
// passB: same structure; recompute dots, partial sum_j exp2(c0 + sim*c1).
// ---------------------------------------------------------------------------
template <int HW, int C, int TI, int JSPLIT>
__global__ __launch_bounds__(256, 4) void passB(
    const uint4* __restrict__ fxB, const uint4* __restrict__ fyB,
    const unsigned* __restrict__ dminEnc, float* __restrict__ Ssum) {
  constexpr int KC = C / 32;
  constexpr int JB = HW / 16;
  constexpr int IBW = 4 * TI;
  constexpr int JPS = JB / JSPLIT;
  const int lane = threadIdx.x & 63, wv = threadIdx.x >> 6, l15 = lane & 15;
  const int sample = blockIdx.x & 7;
  const int rem = blockIdx.x >> 3;
  const int ib = (rem / JSPLIT) * IBW + wv * TI;
  const int jt0 = (rem % JSPLIT) * JPS;
  const size_t sOff = (size_t)sample * JB * KC * 64;
  const uint4* fx = fxB + sOff;
  const uint4* fy = fyB + sOff;

  __shared__ uint4 sbuf[2][KC * 64];

  auto stage = [&](int jt, int buf) {
    const uint4* g = fy + (size_t)jt * KC * 64;
#pragma unroll
    for (int r = 0; r < KC / 4; ++r) {
      const int t = threadIdx.x + r * 256;
      dma16(g + t, &sbuf[buf][t]);
    }
  };

  stage(jt0, 0);

  short8 bf[TI][KC];
#pragma unroll
  for (int ti = 0; ti < TI; ++ti)
#pragma unroll
    for (int kc = 0; kc < KC; ++kc) {
      uint4 t = fx[(size_t)((ib + ti) * KC + kc) * 64 + lane];
      bf[ti][kc] = *(short8*)&t;
    }

  float c0v[TI], c1v[TI];
#pragma unroll
  for (int ti = 0; ti < TI; ++ti) {
    float dmin = decf(dminEnc[(size_t)sample * HW + (ib + ti) * 16 + l15]);
    float dinv = 1.0f / (dmin + EPS);
    c1v[ti] = dinv * KEXP;
    c0v[ti] = (1.0f - dinv) * KEXP;
  }

  float ssum[TI];
#pragma unroll
  for (int ti = 0; ti < TI; ++ti) ssum[ti] = 0.f;

  for (int s = 0; s < JPS; ++s) {
    const int cur = s & 1;
    __syncthreads();
    if (s + 1 < JPS) stage(jt0 + s + 1, cur ^ 1);

    f32x4 acc[TI];
#pragma unroll
    for (int ti = 0; ti < TI; ++ti)
#pragma unroll
      for (int r = 0; r < 4; ++r) acc[ti][r] = 0.f;
#pragma unroll
    for (int kc = 0; kc < KC; ++kc) {
      uint4 t = sbuf[cur][kc * 64 + lane];
      short8 a = *(short8*)&t;
#pragma unroll
      for (int ti = 0; ti < TI; ++ti)
        acc[ti] = __builtin_amdgcn_mfma_f32_16x16x32_bf16(a, bf[ti][kc], acc[ti], 0, 0, 0);
    }
#pragma unroll
    for (int ti = 0; ti < TI; ++ti)
#pragma unroll
      for (int r = 0; r < 4; ++r)
        ssum[ti] += __builtin_amdgcn_exp2f(fmaf(acc[ti][r], c1v[ti], c0v[ti]));
  }

#pragma unroll
  for (int ti = 0; ti < TI; ++ti) {
    float v = ssum[ti];
    v += __shfl_xor(v, 16);
    v += __shfl_xor(v, 32);
    if (lane < 16)
      atomicAdd(&Ssum[(size_t)sample * HW + (ib + ti) * 16 + l15], v);
  }
}

// ---------------------------------------------------------------------------
// reduce_out: one block per sample; atomicAdd(-log(cx+EPS)/16) into out[0].
// ---------------------------------------------------------------------------
__global__ __launch_bounds__(256) void reduce_out(
    const unsigned* __restrict__ dE1, const float* __restrict__ S1,
    const unsigned* __restrict__ dE2, const float* __restrict__ S2,
    float* __restrict__ out) {
  const int s = blockIdx.x;
  const unsigned* dE;
  const float* Sp;
  int HW;
  if (s < 8) { dE = dE1 + (size_t)s * 4096; Sp = S1 + (size_t)s * 4096; HW = 4096; }
  else       { dE = dE2 + (size_t)(s - 8) * 1024; Sp = S2 + (size_t)(s - 8) * 1024; HW = 1024; }
  float t = 0.f;
  for (int i = threadIdx.x; i < HW; i += 256) {
    float dmin = decf(dE[i]);
    float dinv = 1.0f / (dmin + EPS);
    float wmx = __builtin_amdgcn_exp2f((1.0f - dmin * dinv) * KEXP);
    t += wmx / (Sp[i] + EPS);
  }
  __shared__ float red[4];
  t += __shfl_xor(t, 1);  t += __shfl_xor(t, 2);  t += __shfl_xor(t, 4);
  t += __shfl_xor(t, 8);  t += __shfl_xor(t, 16); t += __shfl_xor(t, 32);
  if ((threadIdx.x & 63) == 0) red[threadIdx.x >> 6] = t;
  __syncthreads();
  if (threadIdx.x == 0) {
    float cx = (red[0] + red[1] + red[2] + red[3]) / (float)HW;
    atomicAdd(out, -logf(cx + EPS) * (1.0f / 16.0f));
  }
}

extern "C" void kernel_launch(void* const* d_in, const int* in_sizes, int n_in,
                              void* d_out, int out_size, void* d_ws, size_t ws_size,
                              hipStream_t stream) {
  const float* fx1 = (const float*)d_in[0];  // (8,128,64,64)
  const float* fy1 = (const float*)d_in[1];
  const float* fx2 = (const float*)d_in[2];  // (8,256,32,32)
  const float* fy2 = (const float*)d_in[3];
  float* out = (float*)d_out;

  const int B = 8, HW1 = 4096, HW2 = 1024;

  char* w = (char*)d_ws;
  unsigned* dE1 = (unsigned*)w;                      // 8*4096 u32
  unsigned* dE2 = dE1 + (size_t)B * HW1;             // 8*1024 u32
  float*    S1  = (float*)(dE2 + (size_t)B * HW2);   // 8*4096 f
  float*    S2  = S1 + (size_t)B * HW1;              // 8*1024 f
  uint4*    fx1B = (uint4*)((char*)(S2 + (size_t)B * HW2) + 1024);
  const size_t n1 = (size_t)B * (HW1 / 16) * (128 / 32) * 64;  // 8 MB
  const size_t n2 = (size_t)B * (HW2 / 16) * (256 / 32) * 64;  // 4 MB
  uint4* fy1B = fx1B + n1;
  uint4* fx2B = fy1B + n1;
  uint4* fy2B = fx2B + n2;   // total ~24.4 MB

  prep_all<<<336, 256, 0, stream>>>(fx1, fx1B, fy1, fy1B, fx2, fx2B, fy2, fy2B,
                                    dE1, S1, out);

  // layer1: TI=4 -> block i-width 256, IPB=16, JSPLIT=8 -> 8*16*8 = 1024 blocks
  // layer2: TI=2 -> block i-width 128, IPB=8,  JSPLIT=8 -> 8*8*8  = 512 blocks
  passA<4096, 128, 4, 8><<<1024, 256, 0, stream>>>(fx1B, fy1B, dE1);
  passA<1024, 256, 2, 8><<<512, 256, 0, stream>>>(fx2B, fy2B, dE2);
  passB<4096, 128, 4, 8><<<1024, 256, 0, stream>>>(fx1B, fy1B, dE1, S1);
  passB<1024, 256, 2, 8><<<512, 256, 0, stream>>>(fx2B, fy2B, dE2, S2);

  reduce_out<<<16, 256, 0, stream>>>(dE1, S1, dE2, S2, out);
}